// Round 1
// baseline (83.187 us; speedup 1.0000x reference)
//
#include <hip/hip_runtime.h>
#include <math.h>

#define NB 16
#define NA 19200
#define NT 50
#define NC 80
#define LAMBDA_COORD 5.0f
#define F_EPS 1e-6f

__device__ __forceinline__ float bce_logits(float x, float z) {
    // max(x,0) - x*z + log1p(exp(-|x|))
    return fmaxf(x, 0.0f) - x * z + log1pf(expf(-fabsf(x)));
}

// ---------------- Kernel 1: per-(b,t) argmax over A of IoU ----------------
__global__ void argmax_kernel(const float4* __restrict__ pb,
                              const float* __restrict__ tb,
                              int* __restrict__ best_idx) {
    const int bt = blockIdx.x;          // b*NT + t
    const int b  = bt / NT;
    const float* tgt = tb + (size_t)bt * 4;
    const float tx1 = tgt[0], ty1 = tgt[1], tx2 = tgt[2], ty2 = tgt[3];
    const float area2 = (tx2 - tx1) * (ty2 - ty1);

    float best = -1.0f;
    int   bidx = NA;                    // larger than any valid index
    for (int a = threadIdx.x; a < NA; a += blockDim.x) {
        float4 p = pb[(size_t)b * NA + a];
        float area1 = (p.z - p.x) * (p.w - p.y);
        float ix1 = fmaxf(p.x, tx1), iy1 = fmaxf(p.y, ty1);
        float ix2 = fminf(p.z, tx2), iy2 = fminf(p.w, ty2);
        float inter = fmaxf(ix2 - ix1, 0.0f) * fmaxf(iy2 - iy1, 0.0f);
        float iou = inter / (area1 + area2 - inter + F_EPS);
        if (iou > best) { best = iou; bidx = a; }   // strict > keeps first idx per thread
    }

    __shared__ float sval[256];
    __shared__ int   sidx[256];
    sval[threadIdx.x] = best;
    sidx[threadIdx.x] = bidx;
    __syncthreads();
    for (int s = 128; s > 0; s >>= 1) {
        if ((int)threadIdx.x < s) {
            float v1 = sval[threadIdx.x],     v2 = sval[threadIdx.x + s];
            int   i1 = sidx[threadIdx.x],     i2 = sidx[threadIdx.x + s];
            if (v2 > v1 || (v2 == v1 && i2 < i1)) {  // tie -> smaller index (jnp.argmax)
                sval[threadIdx.x] = v2;
                sidx[threadIdx.x] = i2;
            }
        }
        __syncthreads();
    }
    if (threadIdx.x == 0) best_idx[bt] = sidx[0];
}

// ---------------- Kernel 2: objectness BCE over all (b,a) ----------------
__global__ void obj_kernel(const float* __restrict__ pc,
                           const int* __restrict__ best_idx,
                           float* __restrict__ acc) {
    const int CHUNKS = NA / 256;        // 75
    const int b = blockIdx.x / CHUNKS;
    const int a = (blockIdx.x % CHUNKS) * 256 + threadIdx.x;

    __shared__ int sbi[NT];
    if (threadIdx.x < NT) sbi[threadIdx.x] = best_idx[b * NT + threadIdx.x];
    __syncthreads();

    float z = 0.0f;
    #pragma unroll
    for (int t = 0; t < NT; ++t)
        if (sbi[t] == a) z = 1.0f;

    float x = pc[(size_t)b * NA + a];
    float v = bce_logits(x, z);

    __shared__ float sred[256];
    sred[threadIdx.x] = v;
    __syncthreads();
    for (int s = 128; s > 0; s >>= 1) {
        if ((int)threadIdx.x < s) sred[threadIdx.x] += sred[threadIdx.x + s];
        __syncthreads();
    }
    if (threadIdx.x == 0) atomicAdd(acc + 1, sred[0]);
}

// ---------------- Kernel 3: per-(b,t) CIoU + class BCE ----------------
__global__ void boxcls_kernel(const float* __restrict__ pb,
                              const float* __restrict__ pcls,
                              const float* __restrict__ tb,
                              const int* __restrict__ tl,
                              const int* __restrict__ best_idx,
                              float* __restrict__ acc) {
    const int bt = blockIdx.x;
    const int b  = bt / NT;
    const int bi = best_idx[bt];

    // class BCE: lanes 0..79
    float v = 0.0f;
    if (threadIdx.x < NC) {
        float x = pcls[((size_t)b * NA + bi) * NC + threadIdx.x];
        float z = (tl[bt] == (int)threadIdx.x) ? 1.0f : 0.0f;
        v = bce_logits(x, z);
    }
    __shared__ float sred[128];
    sred[threadIdx.x] = v;
    __syncthreads();
    for (int s = 64; s > 0; s >>= 1) {
        if ((int)threadIdx.x < s) sred[threadIdx.x] += sred[threadIdx.x + s];
        __syncthreads();
    }

    if (threadIdx.x == 0) {
        atomicAdd(acc + 2, sred[0]);

        // CIoU loss (exact reference formula)
        const float* p  = pb + ((size_t)b * NA + bi) * 4;
        const float* tg = tb + (size_t)bt * 4;
        float b1x1 = p[0],  b1y1 = p[1],  b1x2 = p[2],  b1y2 = p[3];
        float b2x1 = tg[0], b2y1 = tg[1], b2x2 = tg[2], b2y2 = tg[3];

        float area1 = (b1x2 - b1x1) * (b1y2 - b1y1);
        float area2 = (b2x2 - b2x1) * (b2y2 - b2y1);
        float iw = fmaxf(fminf(b1x2, b2x2) - fmaxf(b1x1, b2x1), 0.0f);
        float ih = fmaxf(fminf(b1y2, b2y2) - fmaxf(b1y1, b2y1), 0.0f);
        float inter = iw * ih;
        float iou = inter / (area1 + area2 - inter + F_EPS);

        float cdx = fmaxf(b1x2, b2x2) - fminf(b1x1, b2x1);
        float cdy = fmaxf(b1y2, b2y2) - fminf(b1y1, b2y1);
        float c_diag = cdx * cdx + cdy * cdy;

        float cx = (b1x1 + b1x2 - b2x1 - b2x2) * 0.5f;
        float cy = (b1y1 + b1y2 - b2y1 - b2y2) * 0.5f;
        float center_dist = cx * cx + cy * cy;

        float w1 = b1x2 - b1x1, h1 = b1y2 - b1y1;
        float w2 = b2x2 - b2x1, h2 = b2y2 - b2y1;
        float dat = atanf(w2 / h2) - atanf(w1 / h1);
        float vv = (float)(4.0 / (M_PI * M_PI)) * dat * dat;
        float alpha = vv / (1.0f - iou + vv + F_EPS);
        float ciou = iou - center_dist / c_diag - alpha * vv;
        atomicAdd(acc + 0, 1.0f - ciou);
    }
}

// ---------------- Kernel 4: combine ----------------
__global__ void final_kernel(const float* __restrict__ acc, float* __restrict__ out) {
    out[0] = LAMBDA_COORD * acc[0] / (float)(NB * NT)
           + acc[1] / (float)(NB * NA)
           + acc[2] / (float)(NB * NT * NC);
}

extern "C" void kernel_launch(void* const* d_in, const int* in_sizes, int n_in,
                              void* d_out, int out_size, void* d_ws, size_t ws_size,
                              hipStream_t stream) {
    const float* pb   = (const float*)d_in[0];   // (B,A,4)
    const float* pc   = (const float*)d_in[1];   // (B,A,1)
    const float* pcls = (const float*)d_in[2];   // (B,A,C)
    const float* tb   = (const float*)d_in[3];   // (B,T,4)
    const int*   tl   = (const int*)d_in[4];     // (B,T)
    // d_in[5] anchors: unused by the reference

    float* acc      = (float*)d_ws;                  // [0]=box [1]=obj [2]=cls
    int*   best_idx = (int*)((char*)d_ws + 16);      // B*T ints

    hipMemsetAsync(d_ws, 0, 16, stream);

    argmax_kernel<<<NB * NT, 256, 0, stream>>>((const float4*)pb, tb, best_idx);
    obj_kernel<<<NB * (NA / 256), 256, 0, stream>>>(pc, best_idx, acc);
    boxcls_kernel<<<NB * NT, 128, 0, stream>>>(pb, pcls, tb, tl, best_idx, acc);
    final_kernel<<<1, 1, 0, stream>>>(acc, (float*)d_out);
}

// Round 2
// 75.598 us; speedup vs baseline: 1.1004x; 1.1004x over previous
//
#include <hip/hip_runtime.h>
#include <math.h>

#define NB 16
#define NA 19200
#define NT 50
#define NC 80
#define LAMBDA_COORD 5.0f
#define F_EPS 1e-6f

#define OBJ_CHUNKS (NA / 256)           // 75
#define OBJ_BLOCKS (NB * OBJ_CHUNKS)    // 1200
#define BT_BLOCKS  (NB * NT)            // 800

__device__ __forceinline__ float bce_logits(float x, float z) {
    return fmaxf(x, 0.0f) - x * z + log1pf(expf(-fabsf(x)));
}

// ------- Kernel 1: per-(b,t) argmax over A of IoU; block 0 zeroes acc -------
__global__ void argmax_kernel(const float4* __restrict__ pb,
                              const float* __restrict__ tb,
                              int* __restrict__ best_idx,
                              float* __restrict__ acc) {
    if (blockIdx.x == 0 && threadIdx.x < 4) acc[threadIdx.x] = 0.0f;

    const int bt = blockIdx.x;          // b*NT + t
    const int b  = bt / NT;
    const float* tgt = tb + (size_t)bt * 4;
    const float tx1 = tgt[0], ty1 = tgt[1], tx2 = tgt[2], ty2 = tgt[3];
    const float area2 = (tx2 - tx1) * (ty2 - ty1);

    float best = -1.0f;
    int   bidx = NA;
    for (int a = threadIdx.x; a < NA; a += blockDim.x) {
        float4 p = pb[(size_t)b * NA + a];
        float area1 = (p.z - p.x) * (p.w - p.y);
        float ix1 = fmaxf(p.x, tx1), iy1 = fmaxf(p.y, ty1);
        float ix2 = fminf(p.z, tx2), iy2 = fminf(p.w, ty2);
        float inter = fmaxf(ix2 - ix1, 0.0f) * fmaxf(iy2 - iy1, 0.0f);
        float iou = inter / (area1 + area2 - inter + F_EPS);
        if (iou > best) { best = iou; bidx = a; }   // strict > keeps first idx per thread
    }

    __shared__ float sval[256];
    __shared__ int   sidx[256];
    sval[threadIdx.x] = best;
    sidx[threadIdx.x] = bidx;
    __syncthreads();
    for (int s = 128; s > 0; s >>= 1) {
        if ((int)threadIdx.x < s) {
            float v1 = sval[threadIdx.x], v2 = sval[threadIdx.x + s];
            int   i1 = sidx[threadIdx.x], i2 = sidx[threadIdx.x + s];
            if (v2 > v1 || (v2 == v1 && i2 < i1)) {  // tie -> smaller index (jnp.argmax)
                sval[threadIdx.x] = v2;
                sidx[threadIdx.x] = i2;
            }
        }
        __syncthreads();
    }
    if (threadIdx.x == 0) best_idx[bt] = sidx[0];
}

// ------- Kernel 2 (fused): obj BCE (blocks [0,1200)) + CIoU/cls (blocks [1200,2000)) -------
__global__ void fused_loss_kernel(const float* __restrict__ pb,
                                  const float* __restrict__ pc,
                                  const float* __restrict__ pcls,
                                  const float* __restrict__ tb,
                                  const int* __restrict__ tl,
                                  const int* __restrict__ best_idx,
                                  float* __restrict__ acc) {
    __shared__ float sred[256];

    if (blockIdx.x < OBJ_BLOCKS) {
        // ---------------- objectness BCE ----------------
        const int b = blockIdx.x / OBJ_CHUNKS;
        const int a = (blockIdx.x % OBJ_CHUNKS) * 256 + threadIdx.x;

        __shared__ int sbi[NT];
        if (threadIdx.x < NT) sbi[threadIdx.x] = best_idx[b * NT + threadIdx.x];
        __syncthreads();

        float z = 0.0f;
        #pragma unroll
        for (int t = 0; t < NT; ++t)
            if (sbi[t] == a) z = 1.0f;

        float x = pc[(size_t)b * NA + a];
        sred[threadIdx.x] = bce_logits(x, z);
        __syncthreads();
        for (int s = 128; s > 0; s >>= 1) {
            if ((int)threadIdx.x < s) sred[threadIdx.x] += sred[threadIdx.x + s];
            __syncthreads();
        }
        if (threadIdx.x == 0) atomicAdd(acc + 1, sred[0]);
    } else {
        // ---------------- CIoU + class BCE ----------------
        const int bt = blockIdx.x - OBJ_BLOCKS;
        const int b  = bt / NT;
        const int bi = best_idx[bt];

        float v = 0.0f;
        if (threadIdx.x < NC) {
            float x = pcls[((size_t)b * NA + bi) * NC + threadIdx.x];
            float z = (tl[bt] == (int)threadIdx.x) ? 1.0f : 0.0f;
            v = bce_logits(x, z);
        }
        sred[threadIdx.x] = v;
        __syncthreads();
        for (int s = 128; s > 0; s >>= 1) {
            if ((int)threadIdx.x < s) sred[threadIdx.x] += sred[threadIdx.x + s];
            __syncthreads();
        }

        if (threadIdx.x == 0) {
            atomicAdd(acc + 2, sred[0]);

            const float* p  = pb + ((size_t)b * NA + bi) * 4;
            const float* tg = tb + (size_t)bt * 4;
            float b1x1 = p[0],  b1y1 = p[1],  b1x2 = p[2],  b1y2 = p[3];
            float b2x1 = tg[0], b2y1 = tg[1], b2x2 = tg[2], b2y2 = tg[3];

            float area1 = (b1x2 - b1x1) * (b1y2 - b1y1);
            float area2 = (b2x2 - b2x1) * (b2y2 - b2y1);
            float iw = fmaxf(fminf(b1x2, b2x2) - fmaxf(b1x1, b2x1), 0.0f);
            float ih = fmaxf(fminf(b1y2, b2y2) - fmaxf(b1y1, b2y1), 0.0f);
            float inter = iw * ih;
            float iou = inter / (area1 + area2 - inter + F_EPS);

            float cdx = fmaxf(b1x2, b2x2) - fminf(b1x1, b2x1);
            float cdy = fmaxf(b1y2, b2y2) - fminf(b1y1, b2y1);
            float c_diag = cdx * cdx + cdy * cdy;

            float cx = (b1x1 + b1x2 - b2x1 - b2x2) * 0.5f;
            float cy = (b1y1 + b1y2 - b2y1 - b2y2) * 0.5f;
            float center_dist = cx * cx + cy * cy;

            float w1 = b1x2 - b1x1, h1 = b1y2 - b1y1;
            float w2 = b2x2 - b2x1, h2 = b2y2 - b2y1;
            float dat = atanf(w2 / h2) - atanf(w1 / h1);
            float vv = (float)(4.0 / (M_PI * M_PI)) * dat * dat;
            float alpha = vv / (1.0f - iou + vv + F_EPS);
            float ciou = iou - center_dist / c_diag - alpha * vv;
            atomicAdd(acc + 0, 1.0f - ciou);
        }
    }
}

// ---------------- Kernel 3: combine ----------------
__global__ void final_kernel(const float* __restrict__ acc, float* __restrict__ out) {
    out[0] = LAMBDA_COORD * acc[0] / (float)(NB * NT)
           + acc[1] / (float)(NB * NA)
           + acc[2] / (float)(NB * NT * NC);
}

extern "C" void kernel_launch(void* const* d_in, const int* in_sizes, int n_in,
                              void* d_out, int out_size, void* d_ws, size_t ws_size,
                              hipStream_t stream) {
    const float* pb   = (const float*)d_in[0];   // (B,A,4)
    const float* pc   = (const float*)d_in[1];   // (B,A,1)
    const float* pcls = (const float*)d_in[2];   // (B,A,C)
    const float* tb   = (const float*)d_in[3];   // (B,T,4)
    const int*   tl   = (const int*)d_in[4];     // (B,T)

    float* acc      = (float*)d_ws;                  // [0]=box [1]=obj [2]=cls
    int*   best_idx = (int*)((char*)d_ws + 16);      // B*T ints

    argmax_kernel<<<BT_BLOCKS, 256, 0, stream>>>((const float4*)pb, tb, best_idx, acc);
    fused_loss_kernel<<<OBJ_BLOCKS + BT_BLOCKS, 256, 0, stream>>>(pb, pc, pcls, tb, tl, best_idx, acc);
    final_kernel<<<1, 1, 0, stream>>>(acc, (float*)d_out);
}